// Round 5
// baseline (1160.114 us; speedup 1.0000x reference)
//
#include <hip/hip_runtime.h>

#define NI 2048
#define NB 64
#define NC 32
#define DC 16
#define DI 8

static constexpr float SQ_EPS = 1e-7f;

// One routing pass, recomputing u on the fly.
// Grid: (NI/16, 2). Block: 1024 threads = 16 waves, one block per CU.
// Wave w handles capsule i = blockIdx.x*16 + w for 32 batches.
// Lane = (c, dg): c = output capsule, dg = half of the 16-dim output.
//
// R2-R4 post-mortem: the per-lane W fragment (64 floats) kept getting
// rematerialized as in-loop scattered global loads (64 cache lines per
// instr, ~500K line-requests/CU/pass = 360 us); __launch_bounds__ and
// asm-pins both failed to stop it. Fix: load the fragment from an LDS
// staging buffer that is SUBSEQUENTLY OVERWRITTEN (reused as the
// s-accumulator). Remat of the ds_read is then illegal -> W must stay
// in VGPRs. Staging itself is coalesced (2 KB contiguous per c-chunk)
// and one-time.
// MODE 0: uniform coupling 1/32. MODE 1: logits = dot(u, veff),
// veff stored transposed [b][dg][c][8] so the read is coalesced.
template <int MODE>
__global__ __launch_bounds__(1024, 4) void route_pass(
    const float* __restrict__ x, const float* __restrict__ W,
    const float* __restrict__ veff, float* __restrict__ partial)
{
    // Dual-use buffer (68 KB):
    //  phase A: W staging, rounds r=0..3: [c 0..31][512 floats] stride 516
    //           (516%4==0 keeps float4 alignment; one-time, conflicts ok)
    //  phase B: s accumulator [bb 0..31][c 0..31] rows, stride 17 (odd ->
    //           2-way-max ds_add bank aliasing, free per m136)
    __shared__ float s_lds[32 * 32 * 17];  // 17408 floats

    const int tid  = threadIdx.x;
    const int wave = tid >> 6;
    const int lane = tid & 63;
    const int c    = lane & 31;
    const int dg   = lane >> 5;
    const int i    = blockIdx.x * 16 + wave;
    const int b0   = blockIdx.y * 32;

    // ---- phase A: stage W through LDS into registers, 4 rounds ----
    float w[8][8];
    {
        const int cc = tid >> 5;     // 0..31: which c-chunk this thread copies
        const int j  = tid & 31;
        for (int r = 0; r < 4; ++r) {
            // copy W[cc][i0..i0+3][*][*] (2 KB contiguous per cc) into LDS
            const int i0 = blockIdx.x * 16 + r * 4;
            const float4* src =
                reinterpret_cast<const float4*>(W + ((size_t)cc * NI + i0) * 128);
            float4* dst = reinterpret_cast<float4*>(&s_lds[cc * 516]);
#pragma unroll
            for (int k = 0; k < 4; ++k) dst[k * 32 + j] = src[k * 32 + j];
            __syncthreads();
            // waves 4r..4r+3 pull their fragments to registers
            if ((wave >> 2) == r) {
                const int il = wave & 3;
                const float* base = &s_lds[c * 516 + il * 128 + dg * 64];
#pragma unroll
                for (int dd = 0; dd < 8; ++dd) {
                    const float4 lo = *reinterpret_cast<const float4*>(base + dd * 8);
                    const float4 hi = *reinterpret_cast<const float4*>(base + dd * 8 + 4);
                    w[dd][0] = lo.x; w[dd][1] = lo.y; w[dd][2] = lo.z; w[dd][3] = lo.w;
                    w[dd][4] = hi.x; w[dd][5] = hi.y; w[dd][6] = hi.z; w[dd][7] = hi.w;
                }
            }
            __syncthreads();   // readers done before next round's copy
        }
    }

    // ---- phase B: repurpose LDS as the s accumulator ----
    for (int k = tid; k < 32 * 32 * 17; k += 1024) s_lds[k] = 0.0f;
    __syncthreads();

    for (int bbl = 0; bbl < 32; ++bbl) {
        // Stagger waves so no two waves hit the same bb's LDS addresses
        // in lock-step (2w mod 32 distinct for w=0..15).
        const int bb = (bbl + wave * 2) & 31;
        const int b  = b0 + bb;
        const float* xp = x + (size_t)(b * NI + i) * DI;   // wave-uniform
        const float4 x0 = *reinterpret_cast<const float4*>(xp);
        const float4 x1 = *reinterpret_cast<const float4*>(xp + 4);

        float u[8];
#pragma unroll
        for (int dd = 0; dd < 8; ++dd) {
            u[dd] = w[dd][0]*x0.x + w[dd][1]*x0.y + w[dd][2]*x0.z + w[dd][3]*x0.w
                  + w[dd][4]*x1.x + w[dd][5]*x1.y + w[dd][6]*x1.z + w[dd][7]*x1.w;
        }

        float coef;
        if (MODE == 0) {
            coef = 1.0f / 32.0f;
        } else {
            // transposed layout: [b][dg][c][8] -> wave reads 2 KB contiguous
            const float* vp = veff + (((size_t)b * 2 + dg) * 32 + c) * 8;
            const float4 v0 = *reinterpret_cast<const float4*>(vp);
            const float4 v1 = *reinterpret_cast<const float4*>(vp + 4);
            float a = u[0]*v0.x + u[1]*v0.y + u[2]*v0.z + u[3]*v0.w
                    + u[4]*v1.x + u[5]*v1.y + u[6]*v1.z + u[7]*v1.w;
            a += __shfl_xor(a, 32);                  // merge dg halves
            float m = a;
#pragma unroll
            for (int off = 16; off >= 1; off >>= 1)  // softmax over 32 c-lanes
                m = fmaxf(m, __shfl_xor(m, off));
            const float e = __expf(a - m);
            float ssum = e;
#pragma unroll
            for (int off = 16; off >= 1; off >>= 1)
                ssum += __shfl_xor(ssum, off);
            coef = e / ssum;
        }

        float* sl = &s_lds[(bb * 32 + c) * 17 + dg * 8];
#pragma unroll
        for (int dd = 0; dd < 8; ++dd)
            atomicAdd(&sl[dd], coef * u[dd]);
    }
    __syncthreads();

    // Flush this block's 64 KB partial with plain coalesced stores.
    // partial[p][row 0..1023][d 0..15], p = by*128 + bx.
    {
        float* gp = partial +
            (size_t)(blockIdx.y * gridDim.x + blockIdx.x) * (32 * 32 * DC);
#pragma unroll
        for (int k = 0; k < 16; ++k) {
            const int f   = k * 1024 + tid;      // flat [row*16 + d]
            const int row = f >> 4;
            const int d   = f & 15;
            gp[f] = s_lds[row * 17 + d];
        }
    }
}

// Fused 128-way partial reduction + squash.
// Grid 128 x 256 threads: gid -> (b = gid>>9, c = (gid>>4)&31, d = gid&15).
// phase 1: veff  = NI * squash(s)   (transposed layout [b][dg][c][8])
// phase 2: veff += NI * squash(s)   (same layout)
// phase 3: out   = squash(s)        (canonical [b][c][d])
__global__ __launch_bounds__(256) void reduce_squash(
    const float* __restrict__ partial, float* __restrict__ veff,
    float* __restrict__ out, int phase)
{
    const int gid = blockIdx.x * 256 + threadIdx.x;   // 0..32767
    const int b   = gid >> 9;
    const int by  = b >> 5;
    const int bb  = b & 31;
    const int c   = (gid >> 4) & 31;
    const int d   = gid & 15;

    const float* pp = partial + (size_t)(by * 128) * (32 * 32 * DC)
                    + (bb * 32 + c) * DC + d;
    float v = 0.0f;
#pragma unroll 4
    for (int bx = 0; bx < 128; ++bx)
        v += pp[(size_t)bx * (32 * 32 * DC)];

    // |s|^2 across the 16 d-lanes (d = low 4 bits of lane id)
    float sq = v * v;
#pragma unroll
    for (int off = 8; off >= 1; off >>= 1)
        sq += __shfl_xor(sq, off);
    const float scale = sq / ((1.0f + sq) * sqrtf(sq + SQ_EPS));

    if (phase == 3) {
        out[(b * NC + c) * DC + d] = scale * v;
    } else {
        const int idx = (((b * 2) + (d >> 3)) * 32 + c) * 8 + (d & 7);
        const float ns = scale * (float)NI * v;
        if (phase == 1) veff[idx] = ns;
        else            veff[idx] += ns;
    }
}

extern "C" void kernel_launch(void* const* d_in, const int* in_sizes, int n_in,
                              void* d_out, int out_size, void* d_ws, size_t ws_size,
                              hipStream_t stream) {
    (void)in_sizes; (void)n_in; (void)out_size; (void)ws_size;
    const float* x = (const float*)d_in[0];
    const float* W = (const float*)d_in[1];

    float* partial = (float*)d_ws;      // 256 blocks x 64 KB = 16 MiB
    float* veff    = (float*)d_out;     // scratch; phase-3 squash overwrites

    const dim3 grid(NI / 16, 2);

    // ---- iteration 1: uniform coupling
    route_pass<0><<<grid, 1024, 0, stream>>>(x, W, nullptr, partial);
    reduce_squash<<<128, 256, 0, stream>>>(partial, veff, nullptr, 1);

    // ---- iteration 2: logits = NI * <u, v1>
    route_pass<1><<<grid, 1024, 0, stream>>>(x, W, veff, partial);
    reduce_squash<<<128, 256, 0, stream>>>(partial, veff, nullptr, 2);

    // ---- iteration 3: logits = NI * (<u, v1> + <u, v2>)
    route_pass<1><<<grid, 1024, 0, stream>>>(x, W, veff, partial);
    reduce_squash<<<128, 256, 0, stream>>>(partial, nullptr, (float*)d_out, 3);
}

// Round 6
// 414.093 us; speedup vs baseline: 2.8016x; 2.8016x over previous
//
#include <hip/hip_runtime.h>

#define NI 2048
#define NB 64
#define NC 32
#define DC 16
#define DI 8

static constexpr float SQ_EPS = 1e-7f;

// Routing pass with W STREAMED FROM LDS each iteration.
// R2-R5 post-mortem: register-resident W is unachievable — the compiler
// re-materializes the per-lane 64-float fragment as per-iteration scattered
// VMEM loads (~64 cache lines per instr -> ~500K L1 tag lookups/CU/pass =
// 360 us) regardless of __launch_bounds__, asm pins, or LDS round-trips.
// So make the stream cheap instead: LDS has no tag/line bottleneck, and a
// stride-1 wave ds_read_b128 costs ~12 cyc. Each wave processes a b-PAIR
// per W read, halving LDS volume: 4096 wave-b128/CU/pass ~= 49K cyc.
//
// Grid (128 i-blocks, 4 b-quarters) x 512 threads (8 waves).
// Block covers i in [bx*16,+16) as 4 staged sub-tiles of 4 capsules and
// b in [by*16,+16); wave w owns b-pair {by*16+2w, +1}, accumulating
// s[2][8] in registers across all 16 i, then one coalesced partial flush.
// Lane = (c = lane&31, dg = lane>>5) as before. LDS 68 KB -> 2 blocks/CU.
// MODE 0: uniform coupling 1/32. MODE 1: logits = dot(u, veff),
// veff transposed [b][dg][c][8] so reads coalesce.
template <int MODE>
__global__ __launch_bounds__(512, 4) void route_pass(
    const float* __restrict__ x, const float* __restrict__ W,
    const float* __restrict__ veff, float* __restrict__ partial)
{
    // W sub-tile: float4 [il 4][k10 16][dg 2][c 32 + 1 pad] stride 33.
    // In-loop read: 32 c-lanes hit consecutive float4s (two contiguous
    // 512 B runs per instr) -> conflict-free b128 pattern.
    __shared__ float4 wbuf[4224];   // 66 KB
    __shared__ float4 xbuf[128];    // [brel 16][k 8] = x[b][4 i][8 f], 2 KB

    const int tid   = threadIdx.x;
    const int wave  = tid >> 6;
    const int lane  = tid & 63;
    const int c     = lane & 31;
    const int dg    = lane >> 5;
    const int brel0 = wave * 2;
    const int b0    = blockIdx.y * 16 + brel0;    // this wave's b-pair

    float s0[8], s1[8];
#pragma unroll
    for (int dd = 0; dd < 8; ++dd) { s0[dd] = 0.0f; s1[dd] = 0.0f; }

    // veff for the wave's two b's (MODE 1 only), layout [b][dg][c][8]
    float4 va0, va1, vb0, vb1;
    if (MODE == 1) {
        const float4* vp0 = reinterpret_cast<const float4*>(
            veff + (((size_t)b0 * 2 + dg) * 32 + c) * 8);
        va0 = vp0[0]; va1 = vp0[1];
        const float4* vp1 = reinterpret_cast<const float4*>(
            veff + (((size_t)(b0 + 1) * 2 + dg) * 32 + c) * 8);
        vb0 = vp1[0]; vb1 = vp1[1];
    }

    for (int oct = 0; oct < 4; ++oct) {
        const int i0 = blockIdx.x * 16 + oct * 4;
        __syncthreads();               // previous sub-tile's readers done
        // ---- stage W sub-tile: W[c][i0+il][d][f] -> wbuf (coalesced reads)
        {
            const int k   = tid & 31;          // float4 within a (c,i) row
            const int p0  = tid >> 5;          // 0..15
            const int k10 = k & 15, kdg = k >> 4;
            for (int r = 0; r < 8; ++r) {
                const int p  = r * 16 + p0;    // 0..127 = (cc, il)
                const int cc = p >> 2;
                const int il = p & 3;
                wbuf[((il * 16 + k10) * 2 + kdg) * 33 + cc] =
                    reinterpret_cast<const float4*>(W)[
                        ((size_t)cc * NI + i0 + il) * 32 + k];
            }
        }
        // ---- stage x sub-tile (rows of 32 contiguous floats per b)
        if (tid < 128) {
            const int k    = tid & 7;
            const int brel = tid >> 3;
            xbuf[brel * 8 + k] = reinterpret_cast<const float4*>(x)[
                ((size_t)(blockIdx.y * 16 + brel) * NI + i0) * 2 + k];
        }
        __syncthreads();

        for (int il = 0; il < 4; ++il) {
            // x broadcast reads (wave-uniform LDS addresses)
            const float4 xa0 = xbuf[(brel0    ) * 8 + il * 2    ];
            const float4 xa1 = xbuf[(brel0    ) * 8 + il * 2 + 1];
            const float4 xc0 = xbuf[(brel0 + 1) * 8 + il * 2    ];
            const float4 xc1 = xbuf[(brel0 + 1) * 8 + il * 2 + 1];

            float u0[8], u1[8];
#pragma unroll
            for (int dd = 0; dd < 8; ++dd) {
                const float4 wlo = wbuf[((il * 16 + dd * 2    ) * 2 + dg) * 33 + c];
                const float4 whi = wbuf[((il * 16 + dd * 2 + 1) * 2 + dg) * 33 + c];
                u0[dd] = wlo.x*xa0.x + wlo.y*xa0.y + wlo.z*xa0.z + wlo.w*xa0.w
                       + whi.x*xa1.x + whi.y*xa1.y + whi.z*xa1.z + whi.w*xa1.w;
                u1[dd] = wlo.x*xc0.x + wlo.y*xc0.y + wlo.z*xc0.z + wlo.w*xc0.w
                       + whi.x*xc1.x + whi.y*xc1.y + whi.z*xc1.z + whi.w*xc1.w;
            }

            float c0, c1;
            if (MODE == 0) {
                c0 = c1 = 1.0f / 32.0f;
            } else {
                float a0 = u0[0]*va0.x + u0[1]*va0.y + u0[2]*va0.z + u0[3]*va0.w
                         + u0[4]*va1.x + u0[5]*va1.y + u0[6]*va1.z + u0[7]*va1.w;
                float a1 = u1[0]*vb0.x + u1[1]*vb0.y + u1[2]*vb0.z + u1[3]*vb0.w
                         + u1[4]*vb1.x + u1[5]*vb1.y + u1[6]*vb1.z + u1[7]*vb1.w;
                a0 += __shfl_xor(a0, 32);                // merge dg halves
                a1 += __shfl_xor(a1, 32);
                float m0 = a0, m1 = a1;
#pragma unroll
                for (int off = 16; off >= 1; off >>= 1) { // softmax over c
                    m0 = fmaxf(m0, __shfl_xor(m0, off));
                    m1 = fmaxf(m1, __shfl_xor(m1, off));
                }
                const float e0 = __expf(a0 - m0);
                const float e1 = __expf(a1 - m1);
                float t0 = e0, t1 = e1;
#pragma unroll
                for (int off = 16; off >= 1; off >>= 1) {
                    t0 += __shfl_xor(t0, off);
                    t1 += __shfl_xor(t1, off);
                }
                c0 = e0 / t0;
                c1 = e1 / t1;
            }
#pragma unroll
            for (int dd = 0; dd < 8; ++dd) {
                s0[dd] += c0 * u0[dd];
                s1[dd] += c1 * u1[dd];
            }
        }
    }

    // ---- flush the wave's two s-partials (plain coalesced float4 stores)
    // partial floats: [pblk 512][brel 16][dg 2][c 32][8]
    {
        const int pblk = blockIdx.y * gridDim.x + blockIdx.x;   // 0..511
        float4* gp = reinterpret_cast<float4*>(partial) +
            ((size_t)pblk * 16 + brel0) * 128 + dg * 64 + c * 2;
        gp[0] = make_float4(s0[0], s0[1], s0[2], s0[3]);
        gp[1] = make_float4(s0[4], s0[5], s0[6], s0[7]);
        float4* gq = gp + 128;                                  // brel0+1
        gq[0] = make_float4(s1[0], s1[1], s1[2], s1[3]);
        gq[1] = make_float4(s1[4], s1[5], s1[6], s1[7]);
    }
}

// Fused 128-way partial reduction + squash.
// Grid 128 x 256: gid -> (b = gid>>9, c = (gid>>4)&31, d = gid&15).
// phase 1: veff  = NI * squash(s)   (transposed layout [b][dg][c][8])
// phase 2: veff += NI * squash(s)   (same layout)
// phase 3: out   = squash(s)        (canonical [b][c][d])
__global__ __launch_bounds__(256) void reduce_squash(
    const float* __restrict__ partial, float* __restrict__ veff,
    float* __restrict__ out, int phase)
{
    const int gid = blockIdx.x * 256 + threadIdx.x;   // 0..32767
    const int b   = gid >> 9;
    const int c   = (gid >> 4) & 31;
    const int d   = gid & 15;

    // pblk = (b>>4)*128 + ib holds this b's partial at offset (b&15)
    const float* pp = partial
        + ((size_t)(b >> 4) * 128 * 16 + (b & 15)) * 512
        + (d >> 3) * 256 + c * 8 + (d & 7);
    float v = 0.0f;
#pragma unroll 4
    for (int ib = 0; ib < 128; ++ib)
        v += pp[(size_t)ib * (16 * 512)];

    // |s|^2 across the 16 d-lanes (d = low 4 bits of lane id)
    float sq = v * v;
#pragma unroll
    for (int off = 8; off >= 1; off >>= 1)
        sq += __shfl_xor(sq, off);
    const float scale = sq / ((1.0f + sq) * sqrtf(sq + SQ_EPS));

    if (phase == 3) {
        out[(b * NC + c) * DC + d] = scale * v;
    } else {
        const int idx = (((b * 2) + (d >> 3)) * 32 + c) * 8 + (d & 7);
        const float ns = scale * (float)NI * v;
        if (phase == 1) veff[idx] = ns;
        else            veff[idx] += ns;
    }
}

extern "C" void kernel_launch(void* const* d_in, const int* in_sizes, int n_in,
                              void* d_out, int out_size, void* d_ws, size_t ws_size,
                              hipStream_t stream) {
    (void)in_sizes; (void)n_in; (void)out_size; (void)ws_size;
    const float* x = (const float*)d_in[0];
    const float* W = (const float*)d_in[1];

    float* partial = (float*)d_ws;      // 512 slabs x 32 KB = 16 MiB
    float* veff    = (float*)d_out;     // scratch; phase-3 squash overwrites

    const dim3 grid(128, 4);

    // ---- iteration 1: uniform coupling
    route_pass<0><<<grid, 512, 0, stream>>>(x, W, nullptr, partial);
    reduce_squash<<<128, 256, 0, stream>>>(partial, veff, nullptr, 1);

    // ---- iteration 2: logits = NI * <u, v1>
    route_pass<1><<<grid, 512, 0, stream>>>(x, W, veff, partial);
    reduce_squash<<<128, 256, 0, stream>>>(partial, veff, nullptr, 2);

    // ---- iteration 3: logits = NI * (<u, v1> + <u, v2>)
    route_pass<1><<<grid, 512, 0, stream>>>(x, W, veff, partial);
    reduce_squash<<<128, 256, 0, stream>>>(partial, nullptr, (float*)d_out, 3);
}

// Round 7
// 413.002 us; speedup vs baseline: 2.8090x; 1.0026x over previous
//
#include <hip/hip_runtime.h>

#define NI 2048
#define NB 64
#define NC 32
#define DC 16
#define DI 8

static constexpr float SQ_EPS = 1e-7f;

// Routing pass with W STREAMED FROM LDS each iteration.
// R2-R5: register-resident W is unachievable (compiler remats scattered
// VMEM loads, L1-tag-bound, 360 us). R6: LDS-streamed W works (202 us)
// but the allocator targeted 8 waves/EU -> 64 VGPRs -> spilled s/veff to
// scratch = 505 MB/pass of HBM RMW traffic (51% of peak BW!).
// __launch_bounds__'s 2nd arg is only a *minimum* waves/EU; the fix is
// amdgpu_waves_per_eu(4,4), pinning the budget at 128 VGPRs (live set
// ~100) with 4 waves/EU = 2 blocks/CU — exactly what 68 KB LDS allows.
//
// Grid (128 i-blocks, 4 b-quarters) x 512 threads (8 waves).
// Block covers i in [bx*16,+16) as 4 staged sub-tiles of 4 capsules and
// b in [by*16,+16); wave w owns b-pair {by*16+2w, +1}, accumulating
// s[2][8] in registers across all 16 i, then one coalesced partial flush.
// Lane = (c = lane&31, dg = lane>>5).
// MODE 0: uniform coupling 1/32. MODE 1: logits = dot(u, veff),
// veff transposed [b][dg][c][8] so reads coalesce.
template <int MODE>
__global__
__attribute__((amdgpu_flat_work_group_size(512, 512), amdgpu_waves_per_eu(4, 4)))
void route_pass(
    const float* __restrict__ x, const float* __restrict__ W,
    const float* __restrict__ veff, float* __restrict__ partial)
{
    // W sub-tile: float4 [il 4][k10 16][dg 2][c 32 + 1 pad] stride 33.
    // In-loop read: 32 c-lanes hit consecutive float4s -> worst 2-way
    // bank aliasing (free per m136).
    __shared__ float4 wbuf[4224];   // 66 KB
    __shared__ float4 xbuf[128];    // [brel 16][k 8] = x[b][4 i][8 f], 2 KB

    const int tid   = threadIdx.x;
    const int wave  = tid >> 6;
    const int lane  = tid & 63;
    const int c     = lane & 31;
    const int dg    = lane >> 5;
    const int brel0 = wave * 2;
    const int b0    = blockIdx.y * 16 + brel0;    // this wave's b-pair

    float s0[8], s1[8];
#pragma unroll
    for (int dd = 0; dd < 8; ++dd) { s0[dd] = 0.0f; s1[dd] = 0.0f; }

    // veff for the wave's two b's (MODE 1 only), layout [b][dg][c][8]
    float4 va0, va1, vb0, vb1;
    if (MODE == 1) {
        const float4* vp0 = reinterpret_cast<const float4*>(
            veff + (((size_t)b0 * 2 + dg) * 32 + c) * 8);
        va0 = vp0[0]; va1 = vp0[1];
        const float4* vp1 = reinterpret_cast<const float4*>(
            veff + (((size_t)(b0 + 1) * 2 + dg) * 32 + c) * 8);
        vb0 = vp1[0]; vb1 = vp1[1];
    }

    for (int oct = 0; oct < 4; ++oct) {
        const int i0 = blockIdx.x * 16 + oct * 4;
        __syncthreads();               // previous sub-tile's readers done
        // ---- stage W sub-tile: W[c][i0+il][d][f] -> wbuf (coalesced reads)
        {
            const int k   = tid & 31;          // float4 within a (c,i) row
            const int p0  = tid >> 5;          // 0..15
            const int k10 = k & 15, kdg = k >> 4;
            for (int r = 0; r < 8; ++r) {
                const int p  = r * 16 + p0;    // 0..127 = (cc, il)
                const int cc = p >> 2;
                const int il = p & 3;
                wbuf[((il * 16 + k10) * 2 + kdg) * 33 + cc] =
                    reinterpret_cast<const float4*>(W)[
                        ((size_t)cc * NI + i0 + il) * 32 + k];
            }
        }
        // ---- stage x sub-tile (rows of 32 contiguous floats per b)
        if (tid < 128) {
            const int k    = tid & 7;
            const int brel = tid >> 3;
            xbuf[brel * 8 + k] = reinterpret_cast<const float4*>(x)[
                ((size_t)(blockIdx.y * 16 + brel) * NI + i0) * 2 + k];
        }
        __syncthreads();

        for (int il = 0; il < 4; ++il) {
            // x broadcast reads (wave-uniform LDS addresses)
            const float4 xa0 = xbuf[(brel0    ) * 8 + il * 2    ];
            const float4 xa1 = xbuf[(brel0    ) * 8 + il * 2 + 1];
            const float4 xc0 = xbuf[(brel0 + 1) * 8 + il * 2    ];
            const float4 xc1 = xbuf[(brel0 + 1) * 8 + il * 2 + 1];

            float u0[8], u1[8];
#pragma unroll
            for (int dd = 0; dd < 8; ++dd) {
                const float4 wlo = wbuf[((il * 16 + dd * 2    ) * 2 + dg) * 33 + c];
                const float4 whi = wbuf[((il * 16 + dd * 2 + 1) * 2 + dg) * 33 + c];
                u0[dd] = wlo.x*xa0.x + wlo.y*xa0.y + wlo.z*xa0.z + wlo.w*xa0.w
                       + whi.x*xa1.x + whi.y*xa1.y + whi.z*xa1.z + whi.w*xa1.w;
                u1[dd] = wlo.x*xc0.x + wlo.y*xc0.y + wlo.z*xc0.z + wlo.w*xc0.w
                       + whi.x*xc1.x + whi.y*xc1.y + whi.z*xc1.z + whi.w*xc1.w;
            }

            float c0, c1;
            if (MODE == 0) {
                c0 = c1 = 1.0f / 32.0f;
            } else {
                float a0 = u0[0]*va0.x + u0[1]*va0.y + u0[2]*va0.z + u0[3]*va0.w
                         + u0[4]*va1.x + u0[5]*va1.y + u0[6]*va1.z + u0[7]*va1.w;
                float a1 = u1[0]*vb0.x + u1[1]*vb0.y + u1[2]*vb0.z + u1[3]*vb0.w
                         + u1[4]*vb1.x + u1[5]*vb1.y + u1[6]*vb1.z + u1[7]*vb1.w;
                a0 += __shfl_xor(a0, 32);                // merge dg halves
                a1 += __shfl_xor(a1, 32);
                float m0 = a0, m1 = a1;
#pragma unroll
                for (int off = 16; off >= 1; off >>= 1) { // softmax over c
                    m0 = fmaxf(m0, __shfl_xor(m0, off));
                    m1 = fmaxf(m1, __shfl_xor(m1, off));
                }
                const float e0 = __expf(a0 - m0);
                const float e1 = __expf(a1 - m1);
                float t0 = e0, t1 = e1;
#pragma unroll
                for (int off = 16; off >= 1; off >>= 1) {
                    t0 += __shfl_xor(t0, off);
                    t1 += __shfl_xor(t1, off);
                }
                c0 = e0 / t0;
                c1 = e1 / t1;
            }
#pragma unroll
            for (int dd = 0; dd < 8; ++dd) {
                s0[dd] += c0 * u0[dd];
                s1[dd] += c1 * u1[dd];
            }
        }
    }

    // ---- flush the wave's two s-partials (plain coalesced float4 stores)
    // partial floats: [pblk 512][brel 16][dg 2][c 32][8]
    {
        const int pblk = blockIdx.y * gridDim.x + blockIdx.x;   // 0..511
        float4* gp = reinterpret_cast<float4*>(partial) +
            ((size_t)pblk * 16 + brel0) * 128 + dg * 64 + c * 2;
        gp[0] = make_float4(s0[0], s0[1], s0[2], s0[3]);
        gp[1] = make_float4(s0[4], s0[5], s0[6], s0[7]);
        float4* gq = gp + 128;                                  // brel0+1
        gq[0] = make_float4(s1[0], s1[1], s1[2], s1[3]);
        gq[1] = make_float4(s1[4], s1[5], s1[6], s1[7]);
    }
}

// Fused 128-way partial reduction + squash.
// Grid 128 x 256: gid -> (b = gid>>9, c = (gid>>4)&31, d = gid&15).
// phase 1: veff  = NI * squash(s)   (transposed layout [b][dg][c][8])
// phase 2: veff += NI * squash(s)   (same layout)
// phase 3: out   = squash(s)        (canonical [b][c][d])
__global__ __launch_bounds__(256) void reduce_squash(
    const float* __restrict__ partial, float* __restrict__ veff,
    float* __restrict__ out, int phase)
{
    const int gid = blockIdx.x * 256 + threadIdx.x;   // 0..32767
    const int b   = gid >> 9;
    const int c   = (gid >> 4) & 31;
    const int d   = gid & 15;

    // pblk = (b>>4)*128 + ib holds this b's partial at offset (b&15)
    const float* pp = partial
        + ((size_t)(b >> 4) * 128 * 16 + (b & 15)) * 512
        + (d >> 3) * 256 + c * 8 + (d & 7);
    float v = 0.0f;
#pragma unroll 4
    for (int ib = 0; ib < 128; ++ib)
        v += pp[(size_t)ib * (16 * 512)];

    // |s|^2 across the 16 d-lanes (d = low 4 bits of lane id)
    float sq = v * v;
#pragma unroll
    for (int off = 8; off >= 1; off >>= 1)
        sq += __shfl_xor(sq, off);
    const float scale = sq / ((1.0f + sq) * sqrtf(sq + SQ_EPS));

    if (phase == 3) {
        out[(b * NC + c) * DC + d] = scale * v;
    } else {
        const int idx = (((b * 2) + (d >> 3)) * 32 + c) * 8 + (d & 7);
        const float ns = scale * (float)NI * v;
        if (phase == 1) veff[idx] = ns;
        else            veff[idx] += ns;
    }
}

extern "C" void kernel_launch(void* const* d_in, const int* in_sizes, int n_in,
                              void* d_out, int out_size, void* d_ws, size_t ws_size,
                              hipStream_t stream) {
    (void)in_sizes; (void)n_in; (void)out_size; (void)ws_size;
    const float* x = (const float*)d_in[0];
    const float* W = (const float*)d_in[1];

    float* partial = (float*)d_ws;      // 512 slabs x 32 KB = 16 MiB
    float* veff    = (float*)d_out;     // scratch; phase-3 squash overwrites

    const dim3 grid(128, 4);

    // ---- iteration 1: uniform coupling
    route_pass<0><<<grid, 512, 0, stream>>>(x, W, nullptr, partial);
    reduce_squash<<<128, 256, 0, stream>>>(partial, veff, nullptr, 1);

    // ---- iteration 2: logits = NI * <u, v1>
    route_pass<1><<<grid, 512, 0, stream>>>(x, W, veff, partial);
    reduce_squash<<<128, 256, 0, stream>>>(partial, veff, nullptr, 2);

    // ---- iteration 3: logits = NI * (<u, v1> + <u, v2>)
    route_pass<1><<<grid, 512, 0, stream>>>(x, W, veff, partial);
    reduce_squash<<<128, 256, 0, stream>>>(partial, nullptr, (float*)d_out, 3);
}

// Round 8
// 210.174 us; speedup vs baseline: 5.5198x; 1.9650x over previous
//
#include <hip/hip_runtime.h>

#define NI 2048
#define NB 64
#define NC 32
#define DC 16
#define DI 8

static constexpr float SQ_EPS = 1e-7f;

// SSA vector type: first-class LLVM vector -> can NEVER live on the
// scratch stack. R6/R7 post-mortem: float u[8]/s[8] allocas were never
// promoted (505 MB/pass of scratch stack traffic at 51% of HBM peak,
// VGPR_Count stuck at 64). With ext_vector values there is no alloca.
typedef float f8 __attribute__((ext_vector_type(8)));

// Routing pass with W STREAMED FROM LDS each iteration.
// Grid (128 i-blocks, 4 b-quarters) x 512 threads (8 waves).
// Block covers i in [bx*16,+16) as 4 staged sub-tiles of 4 capsules and
// b in [by*16,+16); wave w owns b-pair {by*16+2w, +1}, accumulating
// s0/s1 (f8 each) in registers across all 16 i, then one coalesced flush.
// Lane = (c = lane&31, dg = lane>>5). LDS 68 KB -> 2 blocks/CU.
// MODE 0: uniform coupling 1/32. MODE 1: logits = dot(u, veff),
// veff transposed [b][dg][c][8] so reads coalesce.
template <int MODE>
__global__
__attribute__((amdgpu_flat_work_group_size(512, 512), amdgpu_waves_per_eu(4, 4)))
void route_pass(
    const float* __restrict__ x, const float* __restrict__ W,
    const float* __restrict__ veff, float* __restrict__ partial)
{
    // W sub-tile: float4 [il 4][k10 16][dg 2][c 32 + 1 pad] stride 33.
    // In-loop read: 32 c-lanes hit consecutive float4s -> 2-way max bank
    // aliasing (free per m136).
    __shared__ float4 wbuf[4224];   // 66 KB
    __shared__ float4 xbuf[128];    // [brel 16][k 8] = x[b][4 i][8 f], 2 KB

    const int tid   = threadIdx.x;
    const int wave  = tid >> 6;
    const int lane  = tid & 63;
    const int c     = lane & 31;
    const int dg    = lane >> 5;
    const int brel0 = wave * 2;
    const int b0    = blockIdx.y * 16 + brel0;    // this wave's b-pair

    f8 s0 = {};
    f8 s1 = {};

    // veff for the wave's two b's (MODE 1 only), layout [b][dg][c][8].
    // 32-byte aligned (offset is a multiple of 8 floats).
    f8 va = {}, vb = {};
    if (MODE == 1) {
        va = *reinterpret_cast<const f8*>(
            veff + (((size_t)b0 * 2 + dg) * 32 + c) * 8);
        vb = *reinterpret_cast<const f8*>(
            veff + (((size_t)(b0 + 1) * 2 + dg) * 32 + c) * 8);
    }

    for (int oct = 0; oct < 4; ++oct) {
        const int i0 = blockIdx.x * 16 + oct * 4;
        __syncthreads();               // previous sub-tile's readers done
        // ---- stage W sub-tile: W[c][i0+il][d][f] -> wbuf (coalesced reads)
        {
            const int k   = tid & 31;          // float4 within a (c,i) row
            const int p0  = tid >> 5;          // 0..15
            const int k10 = k & 15, kdg = k >> 4;
            for (int r = 0; r < 8; ++r) {
                const int p  = r * 16 + p0;    // 0..127 = (cc, il)
                const int cc = p >> 2;
                const int il = p & 3;
                wbuf[((il * 16 + k10) * 2 + kdg) * 33 + cc] =
                    reinterpret_cast<const float4*>(W)[
                        ((size_t)cc * NI + i0 + il) * 32 + k];
            }
        }
        // ---- stage x sub-tile (rows of 32 contiguous floats per b)
        if (tid < 128) {
            const int k    = tid & 7;
            const int brel = tid >> 3;
            xbuf[brel * 8 + k] = reinterpret_cast<const float4*>(x)[
                ((size_t)(blockIdx.y * 16 + brel) * NI + i0) * 2 + k];
        }
        __syncthreads();

        for (int il = 0; il < 4; ++il) {
            // x broadcast reads (wave-uniform LDS addresses)
            const float4 xa0 = xbuf[(brel0    ) * 8 + il * 2    ];
            const float4 xa1 = xbuf[(brel0    ) * 8 + il * 2 + 1];
            const float4 xc0 = xbuf[(brel0 + 1) * 8 + il * 2    ];
            const float4 xc1 = xbuf[(brel0 + 1) * 8 + il * 2 + 1];

            f8 u0 = {}, u1 = {};
#pragma unroll
            for (int dd = 0; dd < 8; ++dd) {
                const float4 wl = wbuf[((il * 16 + dd * 2    ) * 2 + dg) * 33 + c];
                const float4 wh = wbuf[((il * 16 + dd * 2 + 1) * 2 + dg) * 33 + c];
                u0[dd] = wl.x*xa0.x + wl.y*xa0.y + wl.z*xa0.z + wl.w*xa0.w
                       + wh.x*xa1.x + wh.y*xa1.y + wh.z*xa1.z + wh.w*xa1.w;
                u1[dd] = wl.x*xc0.x + wl.y*xc0.y + wl.z*xc0.z + wl.w*xc0.w
                       + wh.x*xc1.x + wh.y*xc1.y + wh.z*xc1.z + wh.w*xc1.w;
            }

            float c0, c1;
            if (MODE == 0) {
                c0 = c1 = 1.0f / 32.0f;
            } else {
                float a0 = 0.0f, a1 = 0.0f;
#pragma unroll
                for (int k = 0; k < 8; ++k) {
                    a0 += u0[k] * va[k];
                    a1 += u1[k] * vb[k];
                }
                a0 += __shfl_xor(a0, 32);                // merge dg halves
                a1 += __shfl_xor(a1, 32);
                float m0 = a0, m1 = a1;
#pragma unroll
                for (int off = 16; off >= 1; off >>= 1) { // softmax over c
                    m0 = fmaxf(m0, __shfl_xor(m0, off));
                    m1 = fmaxf(m1, __shfl_xor(m1, off));
                }
                const float e0 = __expf(a0 - m0);
                const float e1 = __expf(a1 - m1);
                float t0 = e0, t1 = e1;
#pragma unroll
                for (int off = 16; off >= 1; off >>= 1) {
                    t0 += __shfl_xor(t0, off);
                    t1 += __shfl_xor(t1, off);
                }
                c0 = e0 / t0;
                c1 = e1 / t1;
            }
            s0 += u0 * c0;
            s1 += u1 * c1;
        }
    }

    // ---- flush the wave's two s-partials (plain coalesced 32 B stores)
    // partial floats: [pblk 512][brel 16][dg 2][c 32][8]
    {
        const int pblk = blockIdx.y * gridDim.x + blockIdx.x;   // 0..511
        float* gp = partial +
            (((size_t)pblk * 16 + brel0) * 128 + dg * 64 + c * 2) * 4;
        *reinterpret_cast<f8*>(gp)       = s0;      // 32 B aligned
        *reinterpret_cast<f8*>(gp + 512) = s1;      // brel0+1
    }
}

// Fused 128-way partial reduction + squash.
// Grid 128 x 256: gid -> (b = gid>>9, c = (gid>>4)&31, d = gid&15).
// phase 1: veff  = NI * squash(s)   (transposed layout [b][dg][c][8])
// phase 2: veff += NI * squash(s)   (same layout)
// phase 3: out   = squash(s)        (canonical [b][c][d])
__global__ __launch_bounds__(256) void reduce_squash(
    const float* __restrict__ partial, float* __restrict__ veff,
    float* __restrict__ out, int phase)
{
    const int gid = blockIdx.x * 256 + threadIdx.x;   // 0..32767
    const int b   = gid >> 9;
    const int c   = (gid >> 4) & 31;
    const int d   = gid & 15;

    // pblk = (b>>4)*128 + ib holds this b's partial at offset (b&15)
    const float* pp = partial
        + ((size_t)(b >> 4) * 128 * 16 + (b & 15)) * 512
        + (d >> 3) * 256 + c * 8 + (d & 7);
    float v = 0.0f;
#pragma unroll 4
    for (int ib = 0; ib < 128; ++ib)
        v += pp[(size_t)ib * (16 * 512)];

    // |s|^2 across the 16 d-lanes (d = low 4 bits of lane id)
    float sq = v * v;
#pragma unroll
    for (int off = 8; off >= 1; off >>= 1)
        sq += __shfl_xor(sq, off);
    const float scale = sq / ((1.0f + sq) * sqrtf(sq + SQ_EPS));

    if (phase == 3) {
        out[(b * NC + c) * DC + d] = scale * v;
    } else {
        const int idx = (((b * 2) + (d >> 3)) * 32 + c) * 8 + (d & 7);
        const float ns = scale * (float)NI * v;
        if (phase == 1) veff[idx] = ns;
        else            veff[idx] += ns;
    }
}

extern "C" void kernel_launch(void* const* d_in, const int* in_sizes, int n_in,
                              void* d_out, int out_size, void* d_ws, size_t ws_size,
                              hipStream_t stream) {
    (void)in_sizes; (void)n_in; (void)out_size; (void)ws_size;
    const float* x = (const float*)d_in[0];
    const float* W = (const float*)d_in[1];

    float* partial = (float*)d_ws;      // 512 slabs x 32 KB = 16 MiB
    float* veff    = (float*)d_out;     // scratch; phase-3 squash overwrites

    const dim3 grid(128, 4);

    // ---- iteration 1: uniform coupling
    route_pass<0><<<grid, 512, 0, stream>>>(x, W, nullptr, partial);
    reduce_squash<<<128, 256, 0, stream>>>(partial, veff, nullptr, 1);

    // ---- iteration 2: logits = NI * <u, v1>
    route_pass<1><<<grid, 512, 0, stream>>>(x, W, veff, partial);
    reduce_squash<<<128, 256, 0, stream>>>(partial, veff, nullptr, 2);

    // ---- iteration 3: logits = NI * (<u, v1> + <u, v2>)
    route_pass<1><<<grid, 512, 0, stream>>>(x, W, veff, partial);
    reduce_squash<<<128, 256, 0, stream>>>(partial, nullptr, (float*)d_out, 3);
}

// Round 9
// 201.183 us; speedup vs baseline: 5.7665x; 1.0447x over previous
//
#include <hip/hip_runtime.h>

#define NI 2048
#define NB 64
#define NC 32
#define DC 16
#define DI 8

static constexpr float SQ_EPS = 1e-7f;

// SSA vector type: first-class LLVM vector -> never an alloca, never
// scratch (R8 lesson: float arrays weren't promoted, 505 MB/pass spill).
typedef float f8 __attribute__((ext_vector_type(8)));

// Routing pass, W streamed from LDS, 4 batches per wave.
// Grid (128 i-blocks, 4 b-quarters) x 256 threads (4 waves).
// Block: i in [bx*16,+16) staged as 4 sub-tiles; b in [by*16,+16);
// wave w owns the b-quad by*16 + w*4 + {0..3} -> each W fragment read
// from LDS is amortized over 4 batches (R8 had 2; W-stream was the
// largest LDS term at ~49K cyc/CU). LDS 68 KB -> 2 blocks/CU;
// amdgpu_waves_per_eu(2,2) = 256-VGPR budget for the ~150-reg live set.
// Lane = (c = lane&31, dg = lane>>5).
// MODE 0: uniform coupling 1/32. MODE 1: logits = dot(u, veff),
// veff transposed [b][dg][c][8].
template <int MODE>
__global__
__attribute__((amdgpu_flat_work_group_size(256, 256), amdgpu_waves_per_eu(2, 2)))
void route_pass(
    const float* __restrict__ x, const float* __restrict__ W,
    const float* __restrict__ veff, float* __restrict__ partial)
{
    // W sub-tile: float4 [il 4][k10 16][kdg 2][c 32 + 1 pad] stride 33.
    __shared__ float4 wbuf[4224];   // 66 KB
    __shared__ float4 xbuf[128];    // [brel 16][k 8] = x[b][4 i][8 f], 2 KB

    const int tid   = threadIdx.x;
    const int wave  = tid >> 6;
    const int lane  = tid & 63;
    const int c     = lane & 31;
    const int dg    = lane >> 5;
    const int brel0 = wave * 4;
    const int b0    = blockIdx.y * 16 + brel0;    // wave's b-quad base

    f8 s0 = {}, s1 = {}, s2 = {}, s3 = {};

    // veff fragments for the 4 b's (MODE 1), transposed [b][dg][c][8]
    f8 va = {}, vb = {}, vc = {}, vd = {};
    if (MODE == 1) {
        va = *reinterpret_cast<const f8*>(veff + (((size_t)(b0+0)*2 + dg)*32 + c)*8);
        vb = *reinterpret_cast<const f8*>(veff + (((size_t)(b0+1)*2 + dg)*32 + c)*8);
        vc = *reinterpret_cast<const f8*>(veff + (((size_t)(b0+2)*2 + dg)*32 + c)*8);
        vd = *reinterpret_cast<const f8*>(veff + (((size_t)(b0+3)*2 + dg)*32 + c)*8);
    }

    for (int oct = 0; oct < 4; ++oct) {
        const int i0 = blockIdx.x * 16 + oct * 4;
        __syncthreads();               // previous sub-tile's readers done
        // ---- stage W sub-tile (coalesced: wave covers 2 full 512 B rows)
        {
            const int k  = tid & 31;          // float4 within a (c,i) row
            const int p0 = tid >> 5;          // 0..7
            const int k10 = k & 15, kdg = k >> 4;
            for (int r = 0; r < 16; ++r) {
                const int p  = r * 8 + p0;    // 0..127 = (cc, il)
                const int cc = p >> 2;
                const int il = p & 3;
                wbuf[((il * 16 + k10) * 2 + kdg) * 33 + cc] =
                    reinterpret_cast<const float4*>(W)[
                        ((size_t)cc * NI + i0 + il) * 32 + k];
            }
        }
        // ---- stage x sub-tile
        if (tid < 128) {
            const int k    = tid & 7;
            const int brel = tid >> 3;
            xbuf[brel * 8 + k] = reinterpret_cast<const float4*>(x)[
                ((size_t)(blockIdx.y * 16 + brel) * NI + i0) * 2 + k];
        }
        __syncthreads();

        for (int il = 0; il < 4; ++il) {
            // x broadcast reads (wave-uniform LDS addresses)
            const float4 xa0 = xbuf[(brel0+0)*8 + il*2], xa1 = xbuf[(brel0+0)*8 + il*2+1];
            const float4 xb0 = xbuf[(brel0+1)*8 + il*2], xb1 = xbuf[(brel0+1)*8 + il*2+1];
            const float4 xc0 = xbuf[(brel0+2)*8 + il*2], xc1 = xbuf[(brel0+2)*8 + il*2+1];
            const float4 xd0 = xbuf[(brel0+3)*8 + il*2], xd1 = xbuf[(brel0+3)*8 + il*2+1];

            f8 u0 = {}, u1 = {}, u2 = {}, u3 = {};
#pragma unroll
            for (int dd = 0; dd < 8; ++dd) {
                const float4 wl = wbuf[((il*16 + dd*2    )*2 + dg)*33 + c];
                const float4 wh = wbuf[((il*16 + dd*2 + 1)*2 + dg)*33 + c];
                u0[dd] = wl.x*xa0.x + wl.y*xa0.y + wl.z*xa0.z + wl.w*xa0.w
                       + wh.x*xa1.x + wh.y*xa1.y + wh.z*xa1.z + wh.w*xa1.w;
                u1[dd] = wl.x*xb0.x + wl.y*xb0.y + wl.z*xb0.z + wl.w*xb0.w
                       + wh.x*xb1.x + wh.y*xb1.y + wh.z*xb1.z + wh.w*xb1.w;
                u2[dd] = wl.x*xc0.x + wl.y*xc0.y + wl.z*xc0.z + wl.w*xc0.w
                       + wh.x*xc1.x + wh.y*xc1.y + wh.z*xc1.z + wh.w*xc1.w;
                u3[dd] = wl.x*xd0.x + wl.y*xd0.y + wl.z*xd0.z + wl.w*xd0.w
                       + wh.x*xd1.x + wh.y*xd1.y + wh.z*xd1.z + wh.w*xd1.w;
            }

            if (MODE == 0) {
                const float cu = 1.0f / 32.0f;
                s0 += u0 * cu; s1 += u1 * cu; s2 += u2 * cu; s3 += u3 * cu;
            } else {
                // Pair-softmax: lower 32-half reduces the even b, upper the
                // odd b, concurrently; one xor-32 merge in, one xor-32
                // coef-swap out. 12 shuffles + 1 exp per pair (was 22 + 2).
#pragma unroll
                for (int pr = 0; pr < 2; ++pr) {
                    const f8& ue = pr ? u2 : u0;
                    const f8& uo = pr ? u3 : u1;
                    const f8& ve = pr ? vc : va;
                    const f8& vo = pr ? vd : vb;
                    float pe = 0.0f, po = 0.0f;
#pragma unroll
                    for (int k = 0; k < 8; ++k) {
                        pe += ue[k] * ve[k];
                        po += uo[k] * vo[k];
                    }
                    // route partial of the OTHER half's b across, keep mine
                    const float send = (dg == 0) ? po : pe;
                    const float recv = __shfl_xor(send, 32);
                    float a = ((dg == 0) ? pe : po) + recv;  // full logit
                    float m = a;
#pragma unroll
                    for (int off = 16; off >= 1; off >>= 1)
                        m = fmaxf(m, __shfl_xor(m, off));
                    const float e = __expf(a - m);
                    float t = e;
#pragma unroll
                    for (int off = 16; off >= 1; off >>= 1)
                        t += __shfl_xor(t, off);
                    const float mine  = e / t;
                    const float other = __shfl_xor(mine, 32);
                    const float ce = (dg == 0) ? mine : other;
                    const float co = (dg == 0) ? other : mine;
                    if (pr == 0) { s0 += u0 * ce; s1 += u1 * co; }
                    else         { s2 += u2 * ce; s3 += u3 * co; }
                }
            }
        }
    }

    // ---- flush the wave's four s-partials (plain coalesced 32 B stores)
    // partial floats: [pblk 512][brel 16][dg 2][c 32][8]
    {
        const int pblk = blockIdx.y * gridDim.x + blockIdx.x;   // 0..511
        float* gp = partial +
            (((size_t)pblk * 16 + brel0) * 128 + dg * 64 + c * 2) * 4;
        *reinterpret_cast<f8*>(gp)        = s0;
        *reinterpret_cast<f8*>(gp +  512) = s1;
        *reinterpret_cast<f8*>(gp + 1024) = s2;
        *reinterpret_cast<f8*>(gp + 1536) = s3;
    }
}

// Fused 128-way partial reduction + squash, float4-vectorized.
// 64 blocks (one per b) x 128 threads: tid -> (c = (tid>>2)&31, dq = tid&3).
// phase 1: veff  = NI * squash(s)   (transposed layout [b][dg][c][8])
// phase 2: veff += NI * squash(s)
// phase 3: out   = squash(s)        (canonical [b][c][d])
__global__ __launch_bounds__(128) void reduce_squash(
    const float* __restrict__ partial, float* __restrict__ veff,
    float* __restrict__ out, int phase)
{
    const int b  = blockIdx.x;
    const int c  = (threadIdx.x >> 2) & 31;
    const int dq = threadIdx.x & 3;          // d-quad: d = dq*4 + j

    // slab layout: [by*128 + ib][brel 16][dg 2][c 32][8]
    const float* base = partial
        + ((size_t)(b >> 4) * 2048 + (b & 15)) * 512
        + (dq >> 1) * 256 + c * 8 + (dq & 1) * 4;
    float4 acc = make_float4(0.f, 0.f, 0.f, 0.f);
#pragma unroll 8
    for (int ib = 0; ib < 128; ++ib) {
        const float4 p = *reinterpret_cast<const float4*>(base + (size_t)ib * 8192);
        acc.x += p.x; acc.y += p.y; acc.z += p.z; acc.w += p.w;
    }

    // |s|^2 across the 4 d-quads (dq = low 2 bits of lane id)
    float sq = acc.x*acc.x + acc.y*acc.y + acc.z*acc.z + acc.w*acc.w;
    sq += __shfl_xor(sq, 1);
    sq += __shfl_xor(sq, 2);
    const float scale = sq / ((1.0f + sq) * sqrtf(sq + SQ_EPS));

    if (phase == 3) {
        float4* op = reinterpret_cast<float4*>(out + ((size_t)b * NC + c) * DC + dq * 4);
        *op = make_float4(scale*acc.x, scale*acc.y, scale*acc.z, scale*acc.w);
    } else {
        const float ns = scale * (float)NI;
        float4* vp = reinterpret_cast<float4*>(
            veff + (((size_t)b * 2 + (dq >> 1)) * 32 + c) * 8 + (dq & 1) * 4);
        if (phase == 1) {
            *vp = make_float4(ns*acc.x, ns*acc.y, ns*acc.z, ns*acc.w);
        } else {
            float4 old = *vp;
            *vp = make_float4(old.x + ns*acc.x, old.y + ns*acc.y,
                              old.z + ns*acc.z, old.w + ns*acc.w);
        }
    }
}

extern "C" void kernel_launch(void* const* d_in, const int* in_sizes, int n_in,
                              void* d_out, int out_size, void* d_ws, size_t ws_size,
                              hipStream_t stream) {
    (void)in_sizes; (void)n_in; (void)out_size; (void)ws_size;
    const float* x = (const float*)d_in[0];
    const float* W = (const float*)d_in[1];

    float* partial = (float*)d_ws;      // 512 slabs x 32 KB = 16 MiB
    float* veff    = (float*)d_out;     // scratch; phase-3 squash overwrites

    const dim3 grid(128, 4);

    // ---- iteration 1: uniform coupling
    route_pass<0><<<grid, 256, 0, stream>>>(x, W, nullptr, partial);
    reduce_squash<<<64, 128, 0, stream>>>(partial, veff, nullptr, 1);

    // ---- iteration 2: logits = NI * <u, v1>
    route_pass<1><<<grid, 256, 0, stream>>>(x, W, veff, partial);
    reduce_squash<<<64, 128, 0, stream>>>(partial, veff, nullptr, 2);

    // ---- iteration 3: logits = NI * (<u, v1> + <u, v2>)
    route_pass<1><<<grid, 256, 0, stream>>>(x, W, veff, partial);
    reduce_squash<<<64, 128, 0, stream>>>(partial, nullptr, (float*)d_out, 3);
}